// Round 7
// baseline (3804.442 us; speedup 1.0000x reference)
//
#include <hip/hip_runtime.h>
#include <hip/hip_fp16.h>

// Problem constants
#define BB 64
#define TT 2048
#define II 128
#define HH 128
#define NG 512  // 4*H

typedef _Float16 f16x8 __attribute__((ext_vector_type(8)));
typedef float f32x4 __attribute__((ext_vector_type(4)));

__device__ __forceinline__ float fast_sigmoid(float x) {
  float t = __builtin_amdgcn_exp2f(-1.4426950408889634f * x);
  return __builtin_amdgcn_rcpf(1.0f + t);
}

__device__ __forceinline__ float fast_tanh(float x) {
  return 2.0f * fast_sigmoid(2.0f * x) - 1.0f;
}

// LDS-only barrier (builtins): lowers to s_waitcnt lgkmcnt(0) + s_barrier,
// does NOT drain vmcnt -> global prefetches stay in flight across it.
__device__ __forceinline__ void bar_lds() {
  __builtin_amdgcn_fence(__ATOMIC_RELEASE, "workgroup", "local");
  __builtin_amdgcn_s_barrier();
  __builtin_amdgcn_fence(__ATOMIC_ACQUIRE, "workgroup", "local");
}

union LDH {
  float4 f4;
  f16x8 h8;
};

// ---------------------------------------------------------------------------
// Transpose Wx0 [512][128] -> WT [128][512] (fp32), tiny
// ---------------------------------------------------------------------------
__global__ void wx0_transpose(const float* __restrict__ W, float* __restrict__ WT) {
  int idx = blockIdx.x * 256 + threadIdx.x;
  if (idx < NG * II) {
    int n = idx >> 7;
    int k = idx & 127;
    WT[k * NG + n] = W[idx];
  }
}

// ---------------------------------------------------------------------------
// Xg = x @ Wx0^T + b0, f16, natural layout [B*T][512]
// ---------------------------------------------------------------------------
__global__ __launch_bounds__(256) void xg0_gemm(const float* __restrict__ X,
                                                const float* __restrict__ WT,  // [128][512]
                                                const float* __restrict__ bias,
                                                __half* __restrict__ Xg) {   // [B*T][512]
  __shared__ float As[64][132];
  __shared__ float Bs[128][64];
  const int m0 = blockIdx.x * 64;
  const int n0 = blockIdx.y * 64;
  const int tid = threadIdx.x;

  {
    const float4* xv = (const float4*)(X + (size_t)m0 * II);
#pragma unroll
    for (int r = 0; r < 8; ++r) {
      int f = tid + 256 * r;
      int m = f >> 5;
      int c4 = f & 31;
      float4 v = xv[m * 32 + c4];
      *(float4*)&As[m][c4 * 4] = v;
    }
  }
  {
#pragma unroll
    for (int r = 0; r < 8; ++r) {
      int f = tid + 256 * r;
      int k = f >> 4;
      int q = f & 15;
      float4 v = *(const float4*)(WT + (size_t)k * NG + n0 + q * 4);
      *(float4*)&Bs[k][q * 4] = v;
    }
  }
  __syncthreads();

  const int tx = tid & 15;
  const int ty = tid >> 4;
  float acc[4][4];
#pragma unroll
  for (int i = 0; i < 4; ++i)
#pragma unroll
    for (int j = 0; j < 4; ++j) acc[i][j] = 0.0f;

#pragma unroll 4
  for (int k = 0; k < 128; ++k) {
    float a0 = As[ty * 4 + 0][k];
    float a1 = As[ty * 4 + 1][k];
    float a2 = As[ty * 4 + 2][k];
    float a3 = As[ty * 4 + 3][k];
    float4 bv = *(const float4*)&Bs[k][tx * 4];
    acc[0][0] = fmaf(a0, bv.x, acc[0][0]);
    acc[0][1] = fmaf(a0, bv.y, acc[0][1]);
    acc[0][2] = fmaf(a0, bv.z, acc[0][2]);
    acc[0][3] = fmaf(a0, bv.w, acc[0][3]);
    acc[1][0] = fmaf(a1, bv.x, acc[1][0]);
    acc[1][1] = fmaf(a1, bv.y, acc[1][1]);
    acc[1][2] = fmaf(a1, bv.z, acc[1][2]);
    acc[1][3] = fmaf(a1, bv.w, acc[1][3]);
    acc[2][0] = fmaf(a2, bv.x, acc[2][0]);
    acc[2][1] = fmaf(a2, bv.y, acc[2][1]);
    acc[2][2] = fmaf(a2, bv.z, acc[2][2]);
    acc[2][3] = fmaf(a2, bv.w, acc[2][3]);
    acc[3][0] = fmaf(a3, bv.x, acc[3][0]);
    acc[3][1] = fmaf(a3, bv.y, acc[3][1]);
    acc[3][2] = fmaf(a3, bv.z, acc[3][2]);
    acc[3][3] = fmaf(a3, bv.w, acc[3][3]);
  }

  float4 bvec = *(const float4*)(bias + n0 + tx * 4);
#pragma unroll
  for (int i = 0; i < 4; ++i) {
    int m = m0 + ty * 4 + i;
    __half2* dst = (__half2*)(Xg + (size_t)m * NG + n0 + tx * 4);
    dst[0] = __halves2half2(__float2half(acc[i][0] + bvec.x),
                            __float2half(acc[i][1] + bvec.y));
    dst[1] = __halves2half2(__float2half(acc[i][2] + bvec.z),
                            __float2half(acc[i][3] + bvec.w));
  }
}

// ---------------------------------------------------------------------------
// MFMA recurrence. One WG per batch element, 512 threads = 8 waves.
// Wave w owns gate rows [w*64, w*64+64) of BOTH layers as 4 row-tiles of 16.
// A-frags (weights, f16) stationary in registers/AGPRs: 48 frags x 4 regs.
// B-frags: h replicated across all 16 mfma columns -> value depends only on
// k -> built from 4 broadcast ds_read_b128 per matvec per wave.
// Frag model (mfma_f32_16x16x32_f16): A[row=l&15][k=(l>>4)*8+j],
// B[k=(l>>4)*8+j][col=l&15], D[row=(l>>4)*4+reg][col=l&15] (m89-verified D).
// Col-0 lanes deposit raw gates to LDS; 256 updater threads add xg/bias,
// activate, and update c/h. Layer-skew: iter i -> g0(i) and g1(i-1),
// 2 LDS-only barriers per step.
// ---------------------------------------------------------------------------
__global__
__attribute__((amdgpu_flat_work_group_size(512, 512)))
void lstm_rec(
    const __half* __restrict__ Xg,    // [B*T][512], includes b0
    const float* __restrict__ Wh0,    // [512][128]
    const float* __restrict__ Wx1,    // [512][128]
    const float* __restrict__ Wh1,    // [512][128]
    const float* __restrict__ b1,     // [512]
    float* __restrict__ out)          // output | hT | cT
{
  const int b = blockIdx.x;
  const int n = threadIdx.x;
  const int w = n >> 6;
  const int l = n & 63;
  const int lrow = l & 15;   // A row / D col
  const int rg = l >> 4;     // k-group / D row-group
  const int r0 = w * 64;

  // ---- stationary weight fragments ----
  f16x8 whf[4][4], wxf[4][4], wvf[4][4];   // [row-tile][k-tile]
#pragma unroll
  for (int tl = 0; tl < 4; ++tl) {
#pragma unroll
    for (int kt = 0; kt < 4; ++kt) {
      const size_t off = (size_t)(r0 + tl * 16 + lrow) * HH + kt * 32 + rg * 8;
      {
        const float4* p = (const float4*)(Wh0 + off);
        float4 v0 = p[0], v1 = p[1];
        f16x8 f;
        f[0] = (_Float16)v0.x; f[1] = (_Float16)v0.y; f[2] = (_Float16)v0.z; f[3] = (_Float16)v0.w;
        f[4] = (_Float16)v1.x; f[5] = (_Float16)v1.y; f[6] = (_Float16)v1.z; f[7] = (_Float16)v1.w;
        whf[tl][kt] = f;
      }
      {
        const float4* p = (const float4*)(Wx1 + off);
        float4 v0 = p[0], v1 = p[1];
        f16x8 f;
        f[0] = (_Float16)v0.x; f[1] = (_Float16)v0.y; f[2] = (_Float16)v0.z; f[3] = (_Float16)v0.w;
        f[4] = (_Float16)v1.x; f[5] = (_Float16)v1.y; f[6] = (_Float16)v1.z; f[7] = (_Float16)v1.w;
        wxf[tl][kt] = f;
      }
      {
        const float4* p = (const float4*)(Wh1 + off);
        float4 v0 = p[0], v1 = p[1];
        f16x8 f;
        f[0] = (_Float16)v0.x; f[1] = (_Float16)v0.y; f[2] = (_Float16)v0.z; f[3] = (_Float16)v0.w;
        f[4] = (_Float16)v1.x; f[5] = (_Float16)v1.y; f[6] = (_Float16)v1.z; f[7] = (_Float16)v1.w;
        wvf[tl][kt] = f;
      }
    }
  }

  __shared__ __align__(16) _Float16 h0p[HH];  // h0(t-1)
  __shared__ __align__(16) _Float16 h1p[HH];  // h1(t-2)
  __shared__ float gbuf[1024];                // raw gates: [0..511] g0, [512..1023] g1

  if (n < HH) {
    h0p[n] = (_Float16)0.0f;
    h1p[n] = (_Float16)0.0f;
  }
  float c0 = 0.0f, c1 = 0.0f, h0v = 0.0f, h1v = 0.0f;

  const __half* XgB = Xg + (size_t)b * TT * NG;
  float* outp = out + (size_t)b * TT * HH;
  float* hT = out + (size_t)BB * TT * HH;   // [2][64][128]
  float* cT = hT + 2 * BB * HH;

  // updater-private state
  __half xg0, xg1, xg2, xg3;
  float bi0 = 0.f, bi1 = 0.f, bi2 = 0.f, bi3 = 0.f;
  if (n < 128) {
    xg0 = XgB[n];
    xg1 = XgB[n + 128];
    xg2 = XgB[n + 256];
    xg3 = XgB[n + 384];
  } else if (n < 256) {
    const int jj = n & 127;
    bi0 = b1[jj];
    bi1 = b1[jj + 128];
    bi2 = b1[jj + 256];
    bi3 = b1[jj + 384];
  }
  __syncthreads();

  const char* h0c = (const char*)h0p + rg * 16;
  const char* h1c = (const char*)h1p + rg * 16;
  const f32x4 zed = {0.f, 0.f, 0.f, 0.f};

#pragma unroll 1
  for (int i = 0; i < TT; ++i) {
    // ---- Phase 1: mfma -> raw g0(i) rows r0..r0+63, raw g1(i-1) ----
    f32x4 a0[4], a1[4];
#pragma unroll
    for (int tl = 0; tl < 4; ++tl) { a0[tl] = zed; a1[tl] = zed; }
#pragma unroll
    for (int kt = 0; kt < 4; ++kt) {
      LDH u;
      u.f4 = *(const float4*)(h0c + kt * 64);
#pragma unroll
      for (int tl = 0; tl < 4; ++tl)
        a0[tl] = __builtin_amdgcn_mfma_f32_16x16x32_f16(whf[tl][kt], u.h8, a0[tl], 0, 0, 0);
#pragma unroll
      for (int tl = 0; tl < 4; ++tl)
        a1[tl] = __builtin_amdgcn_mfma_f32_16x16x32_f16(wxf[tl][kt], u.h8, a1[tl], 0, 0, 0);
    }
#pragma unroll
    for (int kt = 0; kt < 4; ++kt) {
      LDH u;
      u.f4 = *(const float4*)(h1c + kt * 64);
#pragma unroll
      for (int tl = 0; tl < 4; ++tl)
        a1[tl] = __builtin_amdgcn_mfma_f32_16x16x32_f16(wvf[tl][kt], u.h8, a1[tl], 0, 0, 0);
    }
    if (lrow == 0) {
#pragma unroll
      for (int tl = 0; tl < 4; ++tl) {
        *(f32x4*)&gbuf[r0 + tl * 16 + rg * 4] = a0[tl];
        *(f32x4*)&gbuf[512 + r0 + tl * 16 + rg * 4] = a1[tl];
      }
    }
    bar_lds();

    // ---- Phase 2: cell updates ----
    if (n < 128) {
      float gi = fast_sigmoid(gbuf[n] + __half2float(xg0));
      float gf = fast_sigmoid(gbuf[n + 128] + __half2float(xg1));
      float gg = fast_tanh(gbuf[n + 256] + __half2float(xg2));
      float go = fast_sigmoid(gbuf[n + 384] + __half2float(xg3));
      c0 = gf * c0 + gi * gg;
      h0v = go * fast_tanh(c0);
      h0p[n] = (_Float16)h0v;
      const int ip = (i + 1 < TT) ? i + 1 : i;
      const __half* xp = XgB + (size_t)ip * NG + n;
      xg0 = xp[0];
      xg1 = xp[128];
      xg2 = xp[256];
      xg3 = xp[384];
    } else if (n < 256) {
      if (i > 0) {
        const int jj = n & 127;
        float gi = fast_sigmoid(gbuf[512 + jj] + bi0);
        float gf = fast_sigmoid(gbuf[640 + jj] + bi1);
        float gg = fast_tanh(gbuf[768 + jj] + bi2);
        float go = fast_sigmoid(gbuf[896 + jj] + bi3);
        c1 = gf * c1 + gi * gg;
        h1v = go * fast_tanh(c1);
        h1p[jj] = (_Float16)h1v;
        outp[(size_t)(i - 1) * HH + jj] = h1v;
      }
    }
    bar_lds();
  }

  // ---- Epilogue: g1(TT-1) from h0(TT-1), h1(TT-2) ----
  {
    f32x4 a1[4];
#pragma unroll
    for (int tl = 0; tl < 4; ++tl) a1[tl] = zed;
#pragma unroll
    for (int kt = 0; kt < 4; ++kt) {
      LDH u;
      u.f4 = *(const float4*)(h0c + kt * 64);
#pragma unroll
      for (int tl = 0; tl < 4; ++tl)
        a1[tl] = __builtin_amdgcn_mfma_f32_16x16x32_f16(wxf[tl][kt], u.h8, a1[tl], 0, 0, 0);
    }
#pragma unroll
    for (int kt = 0; kt < 4; ++kt) {
      LDH u;
      u.f4 = *(const float4*)(h1c + kt * 64);
#pragma unroll
      for (int tl = 0; tl < 4; ++tl)
        a1[tl] = __builtin_amdgcn_mfma_f32_16x16x32_f16(wvf[tl][kt], u.h8, a1[tl], 0, 0, 0);
    }
    if (lrow == 0) {
#pragma unroll
      for (int tl = 0; tl < 4; ++tl)
        *(f32x4*)&gbuf[512 + r0 + tl * 16 + rg * 4] = a1[tl];
    }
    bar_lds();
    if (n >= 128 && n < 256) {
      const int jj = n & 127;
      float gi = fast_sigmoid(gbuf[512 + jj] + bi0);
      float gf = fast_sigmoid(gbuf[640 + jj] + bi1);
      float gg = fast_tanh(gbuf[768 + jj] + bi2);
      float go = fast_sigmoid(gbuf[896 + jj] + bi3);
      c1 = gf * c1 + gi * gg;
      h1v = go * fast_tanh(c1);
      outp[(size_t)(TT - 1) * HH + jj] = h1v;
    }
  }

  // ---- Final states ----
  if (n < 128) {
    hT[b * HH + n] = h0v;
    cT[b * HH + n] = c0;
  } else if (n < 256) {
    const int jj = n & 127;
    hT[BB * HH + b * HH + jj] = h1v;
    cT[BB * HH + b * HH + jj] = c1;
  }
}

// ---------------------------------------------------------------------------
extern "C" void kernel_launch(void* const* d_in, const int* in_sizes, int n_in,
                              void* d_out, int out_size, void* d_ws, size_t ws_size,
                              hipStream_t stream) {
  const float* x   = (const float*)d_in[0];
  const float* Wx0 = (const float*)d_in[1];
  const float* Wh0 = (const float*)d_in[2];
  const float* b0  = (const float*)d_in[3];
  const float* Wx1 = (const float*)d_in[4];
  const float* Wh1 = (const float*)d_in[5];
  const float* b1  = (const float*)d_in[6];
  float* out = (float*)d_out;

  // Workspace: Xg f16 [B*T][512] = 128 MB, then WT fp32 [128][512]
  __half* Xg = (__half*)d_ws;
  float* WT = (float*)((char*)d_ws + (size_t)BB * TT * NG * sizeof(__half));

  wx0_transpose<<<(NG * II + 255) / 256, 256, 0, stream>>>(Wx0, WT);
  xg0_gemm<<<dim3((BB * TT) / 64, NG / 64), 256, 0, stream>>>(x, WT, b0, Xg);
  lstm_rec<<<BB, 512, 0, stream>>>(Xg, Wh0, Wx1, Wh1, b1, out);
}

// Round 8
// 2583.513 us; speedup vs baseline: 1.4726x; 1.4726x over previous
//
#include <hip/hip_runtime.h>
#include <hip/hip_fp16.h>

// Problem constants
#define BB 64
#define TT 2048
#define II 128
#define HH 128
#define NG 512  // 4*H

typedef _Float16 h2_t __attribute__((ext_vector_type(2)));

#if defined(__has_builtin)
#if __has_builtin(__builtin_amdgcn_fdot2)
#define HAVE_FDOT2 1
#endif
#endif

__device__ __forceinline__ float fdot2f(h2_t a, h2_t b, float c) {
#ifdef HAVE_FDOT2
  return __builtin_amdgcn_fdot2(a, b, c, false);
#else
  return c + (float)a[0] * (float)b[0] + (float)a[1] * (float)b[1];
#endif
}

__device__ __forceinline__ float fast_sigmoid(float x) {
  float t = __builtin_amdgcn_exp2f(-1.4426950408889634f * x);
  return __builtin_amdgcn_rcpf(1.0f + t);
}

// sigmoid(x) normally; tanh(x) = 2*sigmoid(2x)-1 when tanh_sel.
__device__ __forceinline__ float act_gate(float x, bool tanh_sel) {
  float xx = tanh_sel ? 2.0f * x : x;
  float s = fast_sigmoid(xx);
  return tanh_sel ? 2.0f * s - 1.0f : s;
}

__device__ __forceinline__ float fast_tanh(float x) {
  return 2.0f * fast_sigmoid(2.0f * x) - 1.0f;
}

// DPP lane moves within a quad (no LDS pipe). xor1 = quad_perm[1,0,3,2]=0xB1,
// xor2 = quad_perm[2,3,0,1]=0x4E.
__device__ __forceinline__ float dpp_xor1(float x) {
  return __int_as_float(__builtin_amdgcn_update_dpp(0, __float_as_int(x), 0xB1, 0xF, 0xF, true));
}
__device__ __forceinline__ float dpp_xor2(float x) {
  return __int_as_float(__builtin_amdgcn_update_dpp(0, __float_as_int(x), 0x4E, 0xF, 0xF, true));
}

// LDS-only barrier (builtins): s_waitcnt lgkmcnt(0) + s_barrier; vmcnt NOT
// drained -> global prefetches/stores stay in flight.
__device__ __forceinline__ void bar_lds() {
  __builtin_amdgcn_fence(__ATOMIC_RELEASE, "workgroup", "local");
  __builtin_amdgcn_s_barrier();
  __builtin_amdgcn_fence(__ATOMIC_ACQUIRE, "workgroup", "local");
}

union LD4 {
  float4 f4;
  h2_t h[4];
};

// ---------------------------------------------------------------------------
// Transpose Wx0 [512][128] -> WT [128][512] (fp32), tiny
// ---------------------------------------------------------------------------
__global__ void wx0_transpose(const float* __restrict__ W, float* __restrict__ WT) {
  int idx = blockIdx.x * 256 + threadIdx.x;
  if (idx < NG * II) {
    int n = idx >> 7;
    int k = idx & 127;
    WT[k * NG + n] = W[idx];
  }
}

// ---------------------------------------------------------------------------
// Xg = x @ Wx0^T + b0, f16, natural layout [B*T][512]
// ---------------------------------------------------------------------------
__global__ __launch_bounds__(256) void xg0_gemm(const float* __restrict__ X,
                                                const float* __restrict__ WT,  // [128][512]
                                                const float* __restrict__ bias,
                                                __half* __restrict__ Xg) {   // [B*T][512]
  __shared__ float As[64][132];
  __shared__ float Bs[128][64];
  const int m0 = blockIdx.x * 64;
  const int n0 = blockIdx.y * 64;
  const int tid = threadIdx.x;

  {
    const float4* xv = (const float4*)(X + (size_t)m0 * II);
#pragma unroll
    for (int r = 0; r < 8; ++r) {
      int f = tid + 256 * r;
      int m = f >> 5;
      int c4 = f & 31;
      float4 v = xv[m * 32 + c4];
      *(float4*)&As[m][c4 * 4] = v;
    }
  }
  {
#pragma unroll
    for (int r = 0; r < 8; ++r) {
      int f = tid + 256 * r;
      int k = f >> 4;
      int q = f & 15;
      float4 v = *(const float4*)(WT + (size_t)k * NG + n0 + q * 4);
      *(float4*)&Bs[k][q * 4] = v;
    }
  }
  __syncthreads();

  const int tx = tid & 15;
  const int ty = tid >> 4;
  float acc[4][4];
#pragma unroll
  for (int i = 0; i < 4; ++i)
#pragma unroll
    for (int j = 0; j < 4; ++j) acc[i][j] = 0.0f;

#pragma unroll 4
  for (int k = 0; k < 128; ++k) {
    float a0 = As[ty * 4 + 0][k];
    float a1 = As[ty * 4 + 1][k];
    float a2 = As[ty * 4 + 2][k];
    float a3 = As[ty * 4 + 3][k];
    float4 bv = *(const float4*)&Bs[k][tx * 4];
    acc[0][0] = fmaf(a0, bv.x, acc[0][0]);
    acc[0][1] = fmaf(a0, bv.y, acc[0][1]);
    acc[0][2] = fmaf(a0, bv.z, acc[0][2]);
    acc[0][3] = fmaf(a0, bv.w, acc[0][3]);
    acc[1][0] = fmaf(a1, bv.x, acc[1][0]);
    acc[1][1] = fmaf(a1, bv.y, acc[1][1]);
    acc[1][2] = fmaf(a1, bv.z, acc[1][2]);
    acc[1][3] = fmaf(a1, bv.w, acc[1][3]);
    acc[2][0] = fmaf(a2, bv.x, acc[2][0]);
    acc[2][1] = fmaf(a2, bv.y, acc[2][1]);
    acc[2][2] = fmaf(a2, bv.z, acc[2][2]);
    acc[2][3] = fmaf(a2, bv.w, acc[2][3]);
    acc[3][0] = fmaf(a3, bv.x, acc[3][0]);
    acc[3][1] = fmaf(a3, bv.y, acc[3][1]);
    acc[3][2] = fmaf(a3, bv.z, acc[3][2]);
    acc[3][3] = fmaf(a3, bv.w, acc[3][3]);
  }

  float4 bvec = *(const float4*)(bias + n0 + tx * 4);
#pragma unroll
  for (int i = 0; i < 4; ++i) {
    int m = m0 + ty * 4 + i;
    __half2* dst = (__half2*)(Xg + (size_t)m * NG + n0 + tx * 4);
    dst[0] = __halves2half2(__float2half(acc[i][0] + bvec.x),
                            __float2half(acc[i][1] + bvec.y));
    dst[1] = __halves2half2(__float2half(acc[i][2] + bvec.z),
                            __float2half(acc[i][3] + bvec.w));
  }
}

// ---------------------------------------------------------------------------
// Recurrence: one WG per batch element, 512 threads. Thread n = 4j+p owns
// ALL 8 gate rows of hidden unit j (4 per layer) for K-quarter p: 192 f16x2
// weight regs, 192 dot2/step, zero waste. DPP reduce-scatter leaves lane p
// holding gate p's full sum (L0 and L1); each lane activates ONE gate; 3 DPP
// gathers give lane 0 all four -> in-register cell update, 2B h ds_write.
// h0/h1 double-buffered in LDS -> ONE barrier per step. Layer-skewed:
// iter i computes g0(i) and g1(i-1).
// ---------------------------------------------------------------------------
__global__
__attribute__((amdgpu_flat_work_group_size(512, 512)))
void lstm_rec(
    const __half* __restrict__ Xg,    // [B*T][512], includes b0
    const float* __restrict__ Wh0,    // [512][128]
    const float* __restrict__ Wx1,    // [512][128]
    const float* __restrict__ Wh1,    // [512][128]
    const float* __restrict__ b1,     // [512]
    float* __restrict__ out)          // output | hT | cT
{
  const int b = blockIdx.x;
  const int n = threadIdx.x;
  const int j = n >> 2;   // hidden unit
  const int p = n & 3;    // K-quarter AND the gate this lane finalizes
  const bool tsel = (p == 2);  // gate 2 (g) uses tanh

  // ---- weights: rows {j, 128+j, 256+j, 384+j} x K-slice [32p, 32p+32) ----
  h2_t wh[4][16], wx[4][16], wv[4][16];
#pragma unroll
  for (int g = 0; g < 4; ++g) {
    const size_t base = (size_t)(g * 128 + j) * HH + p * 32;
    const float2* ph = (const float2*)(Wh0 + base);
    const float2* px = (const float2*)(Wx1 + base);
    const float2* pv = (const float2*)(Wh1 + base);
#pragma unroll
    for (int k = 0; k < 16; ++k) {
      float2 v;
      v = ph[k]; wh[g][k][0] = (_Float16)v.x; wh[g][k][1] = (_Float16)v.y;
      v = px[k]; wx[g][k][0] = (_Float16)v.x; wx[g][k][1] = (_Float16)v.y;
      v = pv[k]; wv[g][k][0] = (_Float16)v.x; wv[g][k][1] = (_Float16)v.y;
    }
  }
  const float bias1 = b1[p * 128 + j];

  __shared__ __align__(16) _Float16 h0b[2][HH];
  __shared__ __align__(16) _Float16 h1b[2][HH];
  if (n < HH) {
    h0b[0][n] = (_Float16)0.0f;
    h0b[1][n] = (_Float16)0.0f;
    h1b[0][n] = (_Float16)0.0f;
    h1b[1][n] = (_Float16)0.0f;
  }
  float c0 = 0.0f, c1 = 0.0f, h0v = 0.0f, h1v = 0.0f;
  __syncthreads();

  const __half* XgB = Xg + (size_t)b * TT * NG + p * 128 + j;
  float* outp = out + (size_t)b * TT * HH;
  float* hT = out + (size_t)BB * TT * HH;   // [2][64][128]
  float* cT = hT + 2 * BB * HH;

  __half xg_c = XgB[0];

#pragma unroll 1
  for (int i = 0; i < TT; ++i) {
    const int ip = (i + 1 < TT) ? i + 1 : i;
    __half xg_n = XgB[(size_t)ip * NG];   // in flight across the barrier

    // ---- dots: 192 dot2 -> partials of 8 gate rows ----
    const char* H0 = (const char*)h0b[i & 1] + p * 64;
    const char* H1 = (const char*)h1b[i & 1] + p * 64;
    float a0 = 0.f, a1 = 0.f, a2 = 0.f, a3 = 0.f;       // L0 gates i,f,g,o
    float e0 = 0.f, e1 = 0.f, e2 = 0.f, e3 = 0.f;       // L1 gates
#pragma unroll
    for (int q = 0; q < 4; ++q) {
      LD4 u0; u0.f4 = *(const float4*)(H0 + q * 16);
      LD4 u1; u1.f4 = *(const float4*)(H1 + q * 16);
#pragma unroll
      for (int t = 0; t < 4; ++t) {
        const int m = q * 4 + t;
        a0 = fdot2f(wh[0][m], u0.h[t], a0);
        a1 = fdot2f(wh[1][m], u0.h[t], a1);
        a2 = fdot2f(wh[2][m], u0.h[t], a2);
        a3 = fdot2f(wh[3][m], u0.h[t], a3);
        e0 = fdot2f(wx[0][m], u0.h[t], e0);
        e1 = fdot2f(wx[1][m], u0.h[t], e1);
        e2 = fdot2f(wx[2][m], u0.h[t], e2);
        e3 = fdot2f(wx[3][m], u0.h[t], e3);
        e0 = fdot2f(wv[0][m], u1.h[t], e0);
        e1 = fdot2f(wv[1][m], u1.h[t], e1);
        e2 = fdot2f(wv[2][m], u1.h[t], e2);
        e3 = fdot2f(wv[3][m], u1.h[t], e3);
      }
    }

    // ---- reduce-scatter within the quad: lane p <- full sum of gate p ----
    // stage 1 (xor1): keep own-parity gate, exchange the other
    float k01 = (p & 1) ? a1 : a0;
    float u01 = (p & 1) ? a0 : a1;
    float r01 = k01 + dpp_xor1(u01);
    float k23 = (p & 1) ? a3 : a2;
    float u23 = (p & 1) ? a2 : a3;
    float r23 = k23 + dpp_xor1(u23);
    float k45 = (p & 1) ? e1 : e0;
    float u45 = (p & 1) ? e0 : e1;
    float r45 = k45 + dpp_xor1(u45);
    float k67 = (p & 1) ? e3 : e2;
    float u67 = (p & 1) ? e2 : e3;
    float r67 = k67 + dpp_xor1(u67);
    // stage 2 (xor2)
    float kA = (p & 2) ? r23 : r01;
    float uA = (p & 2) ? r01 : r23;
    float sL0 = kA + dpp_xor2(uA);        // raw L0 gate p of unit j
    float kB = (p & 2) ? r67 : r45;
    float uB = (p & 2) ? r45 : r67;
    float sL1 = kB + dpp_xor2(uB);        // raw L1 gate p of unit j

    // ---- one activation per lane ----
    float aL0 = act_gate(sL0 + __half2float(xg_c), tsel);
    float aL1 = act_gate(sL1 + bias1, tsel);

    // ---- gather (i,f,g,o) to lane 0 and update cells ----
    float f0g = dpp_xor1(aL0);   // lane0: f
    float g0g = dpp_xor2(aL0);   // lane0: g
    float o0g = dpp_xor2(f0g);   // lane0: o
    float f1g = dpp_xor1(aL1);
    float g1g = dpp_xor2(aL1);
    float o1g = dpp_xor2(f1g);

    const int wb = (i & 1) ^ 1;
    if (p == 0) {
      c0 = f0g * c0 + aL0 * g0g;
      h0v = o0g * fast_tanh(c0);
      h0b[wb][j] = (_Float16)h0v;
      if (i > 0) {
        c1 = f1g * c1 + aL1 * g1g;
        h1v = o1g * fast_tanh(c1);
        h1b[wb][j] = (_Float16)h1v;
        outp[(size_t)(i - 1) * HH + j] = h1v;
      }
    }
    bar_lds();
    xg_c = xg_n;
  }

  // ---- Epilogue: g1(TT-1) from h0(TT-1), h1(TT-2) (in buf 0) ----
  {
    const char* H0 = (const char*)h0b[0] + p * 64;
    const char* H1 = (const char*)h1b[0] + p * 64;
    float e0 = 0.f, e1 = 0.f, e2 = 0.f, e3 = 0.f;
#pragma unroll
    for (int q = 0; q < 4; ++q) {
      LD4 u0; u0.f4 = *(const float4*)(H0 + q * 16);
      LD4 u1; u1.f4 = *(const float4*)(H1 + q * 16);
#pragma unroll
      for (int t = 0; t < 4; ++t) {
        const int m = q * 4 + t;
        e0 = fdot2f(wx[0][m], u0.h[t], e0);
        e1 = fdot2f(wx[1][m], u0.h[t], e1);
        e2 = fdot2f(wx[2][m], u0.h[t], e2);
        e3 = fdot2f(wx[3][m], u0.h[t], e3);
        e0 = fdot2f(wv[0][m], u1.h[t], e0);
        e1 = fdot2f(wv[1][m], u1.h[t], e1);
        e2 = fdot2f(wv[2][m], u1.h[t], e2);
        e3 = fdot2f(wv[3][m], u1.h[t], e3);
      }
    }
    float k45 = (p & 1) ? e1 : e0;
    float u45 = (p & 1) ? e0 : e1;
    float r45 = k45 + dpp_xor1(u45);
    float k67 = (p & 1) ? e3 : e2;
    float u67 = (p & 1) ? e2 : e3;
    float r67 = k67 + dpp_xor1(u67);
    float kB = (p & 2) ? r67 : r45;
    float uB = (p & 2) ? r45 : r67;
    float sL1 = kB + dpp_xor2(uB);
    float aL1 = act_gate(sL1 + bias1, tsel);
    float f1g = dpp_xor1(aL1);
    float g1g = dpp_xor2(aL1);
    float o1g = dpp_xor2(f1g);
    if (p == 0) {
      c1 = f1g * c1 + aL1 * g1g;
      h1v = o1g * fast_tanh(c1);
      outp[(size_t)(TT - 1) * HH + j] = h1v;
      // final states
      hT[b * HH + j] = h0v;
      hT[BB * HH + b * HH + j] = h1v;
      cT[b * HH + j] = c0;
      cT[BB * HH + b * HH + j] = c1;
    }
  }
}

// ---------------------------------------------------------------------------
extern "C" void kernel_launch(void* const* d_in, const int* in_sizes, int n_in,
                              void* d_out, int out_size, void* d_ws, size_t ws_size,
                              hipStream_t stream) {
  const float* x   = (const float*)d_in[0];
  const float* Wx0 = (const float*)d_in[1];
  const float* Wh0 = (const float*)d_in[2];
  const float* b0  = (const float*)d_in[3];
  const float* Wx1 = (const float*)d_in[4];
  const float* Wh1 = (const float*)d_in[5];
  const float* b1  = (const float*)d_in[6];
  float* out = (float*)d_out;

  // Workspace: Xg f16 [B*T][512] = 128 MB, then WT fp32 [128][512]
  __half* Xg = (__half*)d_ws;
  float* WT = (float*)((char*)d_ws + (size_t)BB * TT * NG * sizeof(__half));

  wx0_transpose<<<(NG * II + 255) / 256, 256, 0, stream>>>(Wx0, WT);
  xg0_gemm<<<dim3((BB * TT) / 64, NG / 64), 256, 0, stream>>>(x, WT, b0, Xg);
  lstm_rec<<<BB, 512, 0, stream>>>(Xg, Wh0, Wx1, Wh1, b1, out);
}